// Round 13
// baseline (636.529 us; speedup 1.0000x reference)
//
#include <hip/hip_runtime.h>
#include <hip/hip_bf16.h>
#include <math.h>

#define B 16
#define L 96
#define N 512
#define D 512
#define H 8
#define E 64
#define DFF 2048
#define T 516
#define PRED 96
#define NMARK 4
#define VTS 576    // vt row stride (keys, padded from 516 to 9*64)
#define NCHUNK 9   // key chunks of 64

typedef __attribute__((ext_vector_type(8))) short bf16x8;
typedef __attribute__((ext_vector_type(4))) float f32x4;

// ---- workspace layout (BYTE offsets). Total 80,412,672 B ----
#define WS_MEAN 0              // f32 [B,N]
#define WS_STD  32768          // f32 [B,N]
#define WS_GD   65536          // bf16 [B,N,N] = 8,388,608 B
#define WS_X    8454144        // bf16 [B,T,D] residual stream R
#define WS_XB   25362432       // bf16 [B,T,D] ctxb
#define WS_WTS  33816576       // bf16 transposed weights, 12,779,520 B
#define WS_QB   46596096       // bf16 [B,T,D]; also tokb(bf16), ffn base
#define WS_KB   55050240       // bf16 [B,T,D]; also xt(f32)
#define WS_VT   63504384       // bf16 [B,H,64,VTS] = 9,437,184 B; also ntb(bf16)
#define VT_BYTES 9437184
// ffnb = WS_QB .. WS_QB + 8256*2048*2 = 80,412,672 (spans qb,kb,vt; time-disjoint)

// weight-arena element offsets (bf16 elements from WS_WTS)
#define WT_QKV  0u          // [2][1536][512]: rows 0..511 Q, 512..1023 K, 1024..1535 V
#define WT_WO   1572864u    // [2][512][512]
#define WT_W1   2097152u    // [2][2048][512]
#define WT_W2   4194304u    // [2][512][2048]
#define WT_EMB  6291456u    // [512][96]
#define WT_PROJ 6340608u    // [96][512]

// ---------- RevIN stats ----------
__global__ void revin_stats_kernel(const float* __restrict__ x, float* __restrict__ mean,
                                   float* __restrict__ stdv) {
    int i = blockIdx.x * blockDim.x + threadIdx.x;
    if (i >= B * N) return;
    int b = i >> 9;
    int n = i & (N - 1);
    const float* p = x + (size_t)b * L * N + n;
    float s = 0.f, ss = 0.f;
    for (int l = 0; l < L; ++l) {
        float v = p[(size_t)l * N];
        s += v; ss += v * v;
    }
    float m = s / (float)L;
    float var = ss / (float)L - m * m;
    mean[i] = m;
    stdv[i] = sqrtf(fmaxf(var, 0.f) + 1e-5f);
}

// ---------- normalize + transpose: xt[b,n,l] (f32) + tokb[b,n,l] (bf16) ----------
__global__ void norm_transpose_kernel(const float* __restrict__ x, const float* __restrict__ mean,
                                      const float* __restrict__ stdv, const float* __restrict__ gamma,
                                      const float* __restrict__ beta, float* __restrict__ xt,
                                      __hip_bfloat16* __restrict__ tokb) {
    int idx = blockIdx.x * blockDim.x + threadIdx.x;
    if (idx >= B * N * L) return;
    int l = idx % L;
    int n = (idx / L) % N;
    int b = idx / (L * N);
    float v = x[((size_t)b * L + l) * N + n];
    int bn = b * N + n;
    float o = (v - mean[bn]) / stdv[bn] * gamma[n] + beta[n];
    xt[idx] = o;
    tokb[((size_t)b * T + n) * L + l] = __float2bfloat16(o);
}

// ---------- fill token mark rows N..T-1 ----------
__global__ void build_mark_kernel(const float* __restrict__ xmark, __hip_bfloat16* __restrict__ tok) {
    int idx = blockIdx.x * blockDim.x + threadIdx.x;
    if (idx >= B * NMARK * L) return;
    int l = idx % L;
    int t = (idx / L) % NMARK;
    int b = idx / (L * NMARK);
    tok[((size_t)b * T + N + t) * L + l] =
        __float2bfloat16(xmark[((size_t)b * L + l) * NMARK + t]);
}

// ---------- trend + normalized trend rows ntb[b,n,l] (bf16) ----------
__global__ void trend_nt_kernel(const float* __restrict__ xt, const float* __restrict__ tp_w1,
                                const float* __restrict__ tp_b1, const float* __restrict__ tp_w2,
                                const float* __restrict__ tp_b2, __hip_bfloat16* __restrict__ ntb) {
    int bn = blockIdx.x;
    __shared__ float xr[96];
    __shared__ float P[97];
    __shared__ float wt[4];
    __shared__ float tr[96];
    __shared__ float nrm;
    int tid = threadIdx.x;
    if (tid < 96) xr[tid] = xt[(size_t)bn * 96 + tid];
    __syncthreads();
    if (tid == 0) {
        float s = 0.f, ss = 0.f;
        P[0] = 0.f;
        for (int l = 0; l < 96; ++l) { s += xr[l]; P[l + 1] = s; ss += xr[l] * xr[l]; }
        float m = s / 96.f;
        float var = ss / 96.f - m * m;
        float sd = sqrtf(fmaxf(var, 0.f) + 1e-6f);
        float h[16];
        for (int j = 0; j < 16; ++j) {
            float t = m * tp_w1[j] + sd * tp_w1[16 + j] + tp_b1[j];
            h[j] = fmaxf(t, 0.f);
        }
        float lg[4];
        for (int w = 0; w < 4; ++w) {
            float t = tp_b2[w];
            for (int j = 0; j < 16; ++j) t += h[j] * tp_w2[j * 4 + w];
            lg[w] = t;
        }
        float mx = fmaxf(fmaxf(lg[0], lg[1]), fmaxf(lg[2], lg[3]));
        float es = 0.f;
        for (int w = 0; w < 4; ++w) { lg[w] = expf(lg[w] - mx); es += lg[w]; }
        for (int w = 0; w < 4; ++w) wt[w] = lg[w] / es;
    }
    __syncthreads();
    const int WS[4] = {4, 8, 12, 24};
    if (tid < 96) {
        int l = tid;
        float t = 0.f;
        for (int wi = 0; wi < 4; ++wi) {
            int w = WS[wi];
            int lo = l - w + 1;
            float s;
            if (lo >= 0) s = P[l + 1] - P[lo];
            else         s = P[l + 1] - P[0] + (float)(-lo) * xr[0];
            t += (s / (float)w) * wt[wi];
        }
        tr[l] = t;
    }
    __syncthreads();
    if (tid == 0) {
        float s = 0.f;
        for (int l = 0; l < 96; ++l) s += tr[l] * tr[l];
        nrm = fmaxf(sqrtf(s), 1e-12f);
    }
    __syncthreads();
    if (tid < 96) ntb[(size_t)bn * 96 + tid] = __float2bfloat16(tr[tid] / nrm);
}

// XOR swizzle (BK=32): LDS slot sl of row holds global segment sl^((row>>1)&3)
#define SWZM(row) (((row) >> 1) & 3)

// ---------- guidance via MFMA: gd = sigmoid(nt @ nt^T), per batch ----------
__global__ __launch_bounds__(256, 2) void guide_mfma_kernel(
    const __hip_bfloat16* __restrict__ nt, __hip_bfloat16* __restrict__ gd) {
    __shared__ __align__(16) __hip_bfloat16 As[64 * 32];
    __shared__ __align__(16) __hip_bfloat16 Bs[64 * 32];
    int id = blockIdx.x;
    int b = id >> 6;
    int tile = id & 63;
    int bm = (tile >> 3) * 64;
    int bn = (tile & 7) * 64;
    const __hip_bfloat16* base = nt + (size_t)b * N * 96;
    int tid = threadIdx.x;
    int lane = tid & 63;
    int wave = tid >> 6;
    int col = lane & 15;
    int quad = lane >> 4;
    int wm = (wave & 1) * 32;
    int wn = (wave >> 1) * 32;
    f32x4 acc[2][2];
    #pragma unroll
    for (int i = 0; i < 2; ++i)
        #pragma unroll
        for (int j = 0; j < 2; ++j) acc[i][j] = (f32x4){0.f, 0.f, 0.f, 0.f};

    #pragma unroll
    for (int k0 = 0; k0 < 96; k0 += 32) {
        {
            int cbase = wave * 64;
            int c = cbase + lane;
            int row = c >> 2;
            int g = (c & 3) ^ SWZM(row);
            const __hip_bfloat16* ga = base + (size_t)(bm + row) * 96 + k0 + g * 8;
            __builtin_amdgcn_global_load_lds(
                (const __attribute__((address_space(1))) void*)ga,
                (__attribute__((address_space(3))) void*)(As + (size_t)cbase * 8), 16, 0, 0);
            const __hip_bfloat16* gb = base + (size_t)(bn + row) * 96 + k0 + g * 8;
            __builtin_amdgcn_global_load_lds(
                (const __attribute__((address_space(1))) void*)gb,
                (__attribute__((address_space(3))) void*)(Bs + (size_t)cbase * 8), 16, 0, 0);
        }
        __syncthreads();
        bf16x8 af[2], bfr[2];
        #pragma unroll
        for (int i = 0; i < 2; ++i) {
            int ra = wm + i * 16 + col;
            af[i] = *(const bf16x8*)(const void*)&As[(ra * 4 + (quad ^ SWZM(ra))) * 8];
        }
        #pragma unroll
        for (int j = 0; j < 2; ++j) {
            int rb = wn + j * 16 + col;
            bfr[j] = *(const bf16x8*)(const void*)&Bs[(rb * 4 + (quad ^ SWZM(rb))) * 8];
        }
        #pragma unroll
        for (int i = 0; i < 2; ++i)
            #pragma unroll
            for (int j = 0; j < 2; ++j)
                acc[i][j] = __builtin_amdgcn_mfma_f32_16x16x32_bf16(af[i], bfr[j], acc[i][j], 0, 0, 0);
        __syncthreads();
    }
    #pragma unroll
    for (int i = 0; i < 2; ++i) {
        int gmb = bm + wm + i * 16 + quad * 4;
        #pragma unroll
        for (int j = 0; j < 2; ++j) {
            int gn = bn + wn + j * 16 + col;
            #pragma unroll
            for (int r = 0; r < 4; ++r) {
                int gm = gmb + r;
                float sig = __builtin_amdgcn_rcpf(1.f + __expf(-acc[i][j][r]));
                gd[((size_t)b * N + gm) * N + gn] = __float2bfloat16(sig);
            }
        }
    }
}

// ---------- weight transpose+convert: fp32 [K,N] -> bf16 [N,K] ----------
__global__ void wconv_kernel(const float* __restrict__ wq, const float* __restrict__ wk,
                             const float* __restrict__ wv, const float* __restrict__ wo,
                             const float* __restrict__ w1, const float* __restrict__ w2,
                             const float* __restrict__ emb, const float* __restrict__ proj,
                             __hip_bfloat16* __restrict__ wts) {
    int bid = blockIdx.x;
    const float* src; __hip_bfloat16* dst; int K, Nn, tloc;
    if (bid < 2048) {
        int seg = bid >> 9;          // 0=wq 1=wk 2=wv 3=wo
        int t = bid & 511;
        int layer = t >> 8;
        tloc = t & 255;
        K = 512; Nn = 512;
        const float* bases[4] = {wq, wk, wv, wo};
        src = bases[seg] + (size_t)layer * 512 * 512;
        if (seg < 3)
            dst = wts + WT_QKV + (size_t)layer * 1536 * 512 + (size_t)seg * 512 * 512;
        else
            dst = wts + WT_WO + (size_t)layer * 512 * 512;
    } else if (bid < 4096) {
        int t = bid - 2048;
        int layer = t >> 10;
        tloc = t & 1023;
        K = 512; Nn = 2048;
        src = w1 + (size_t)layer * 512 * 2048;
        dst = wts + WT_W1 + (size_t)layer * 2048 * 512;
    } else if (bid < 6144) {
        int t = bid - 4096;
        int layer = t >> 10;
        tloc = t & 1023;
        K = 2048; Nn = 512;
        src = w2 + (size_t)layer * 2048 * 512;
        dst = wts + WT_W2 + (size_t)layer * 512 * 2048;
    } else if (bid < 6192) {
        tloc = bid - 6144;
        K = 96; Nn = 512;
        src = emb; dst = wts + WT_EMB;
    } else {
        tloc = bid - 6192;
        K = 512; Nn = 96;
        src = proj; dst = wts + WT_PROJ;
    }
    int ntile = Nn >> 5;
    int tk = tloc / ntile, tn = tloc % ntile;
    int k0 = tk * 32, n0 = tn * 32;
    __shared__ float ld[32][33];
    int tid = threadIdx.x;
    for (int i = tid; i < 1024; i += 256) {
        int r = i >> 5, c = i & 31;
        ld[r][c] = src[(size_t)(k0 + r) * Nn + n0 + c];
    }
    __syncthreads();
    for (int i = tid; i < 1024; i += 256) {
        int r = i >> 5, c = i & 31;
        dst[(size_t)(n0 + r) * K + k0 + c] = __float2bfloat16(ld[c][r]);
    }
}

__device__ __forceinline__ float gelu_tanh(float v) {
    // (1+tanh z)/2 == sigmoid(2z): mathematically identical, 2 transcendentals
    float y = 1.5957691216057308f * v * fmaf(0.044715f, v * v, 1.f);
    float e = __expf(-y);
    return v * __builtin_amdgcn_rcpf(1.f + e);
}

// ---------- templated MFMA bf16 GEMM: TM x TN tile, BK=32, 4 waves ----------
// Ping-pong LDS: stage(k+1) issued before iter k's MFMAs, so the next
// barrier's forced vmcnt(0) drain finds loads already complete.
template<int TM, int TN>
__global__ __launch_bounds__(256, 2) void mfma_gemm_t(
    const __hip_bfloat16* __restrict__ A, const __hip_bfloat16* __restrict__ Wt,
    const float* __restrict__ bias, const __hip_bfloat16* __restrict__ resB,
    __hip_bfloat16* __restrict__ outB,
    int M, int Nn, int K, int act, int nbm, int nbn) {
    constexpr int WM = TM / 2, WN = TN / 2;
    constexpr int FI = WM / 16, FJ = WN / 16;
    __shared__ __align__(16) __hip_bfloat16 As[2][TM * 32];
    __shared__ __align__(16) __hip_bfloat16 Bs[2][TN * 32];
    int id = blockIdx.x;
    int xcd = id & 7, slot = id >> 3;
    int bmb = xcd + 8 * (slot / nbn);
    int bnb = slot % nbn;
    if (bmb >= nbm) return;
    int bm = bmb * TM;
    int bn = bnb * TN;
    int tid = threadIdx.x;
    int lane = tid & 63;
    int wave = tid >> 6;
    int col = lane & 15;
    int quad = lane >> 4;
    int wm = (wave & 1) * WM;
    int wn = (wave >> 1) * WN;
    f32x4 acc[FI][FJ];
    #pragma unroll
    for (int i = 0; i < FI; ++i)
        #pragma unroll
        for (int j = 0; j < FJ; ++j) acc[i][j] = (f32x4){0.f, 0.f, 0.f, 0.f};

    auto stage = [&](int itk, int bufi) {
        int k0 = itk << 5;
        #pragma unroll
        for (int it = 0; it < TM / 64; ++it) {
            int cbase = it * 256 + wave * 64;
            int c = cbase + lane;
            int row = c >> 2;
            int g = (c & 3) ^ SWZM(row);
            int gm = bm + row; if (gm >= M) gm = M - 1;
            const __hip_bfloat16* ga = A + (size_t)gm * K + k0 + g * 8;
            __builtin_amdgcn_global_load_lds(
                (const __attribute__((address_space(1))) void*)ga,
                (__attribute__((address_space(3))) void*)(As[bufi] + (size_t)cbase * 8), 16, 0, 0);
        }
        #pragma unroll
        for (int it = 0; it < TN / 64; ++it) {
            int cbase = it * 256 + wave * 64;
            int c = cbase + lane;
            int row = c >> 2;
            int g = (c & 3) ^ SWZM(row);
            int gn = bn + row; if (gn >= Nn) gn = Nn - 1;
            const __hip_bfloat16* gb = Wt + (size_t)gn * K + k0 + g * 8;
            __builtin_amdgcn_global_load_lds(
                (const __attribute__((address_space(1))) void*)gb,
                (__attribute__((address_space(3))) void*)(Bs[bufi] + (size_t)cbase * 8), 16, 0, 0);
        }
    };

    const int nIt = K >> 5;
    stage(0, 0);
    for (int itk = 0; itk < nIt; ++itk) {
        __syncthreads();   // drains this iter's staged loads; protects buffer reuse
        if (itk + 1 < nIt) stage(itk + 1, (itk + 1) & 1);
        const __hip_bfloat16* Ac = As[itk & 1];
        const __hip_bfloat16* Bc = Bs[itk & 1];
        bf16x8 af[FI], bfr[FJ];
        #pragma unroll
        for (int i = 0; i < FI; ++i) {
            int ra = wm + i * 16 + col;
            af[i] = *(const bf16x8*)(const void*)&Ac[(ra * 4 + (quad ^ SWZM(ra))) * 8];
        }
        #pragma unroll
        for (int j = 0; j < FJ; ++j) {
            int rb = wn + j * 16 + col;
            bfr[j] = *(const bf16x8*)(const void*)&Bc[(rb * 4 + (quad ^ SWZM(rb))) * 8];
        }
        #pragma unroll
        for (int i = 0; i < FI; ++i)
            #pragma unroll
            for (int j = 0; j < FJ; ++j)
                acc[i][j] = __builtin_amdgcn_mfma_f32_16x16x32_bf16(af[i], bfr[j], acc[i][j], 0, 0, 0);
    }
    #pragma unroll
    for (int i = 0; i < FI; ++i) {
        int gmb = bm + wm + i * 16 + quad * 4;
        #pragma unroll
        for (int j = 0; j < FJ; ++j) {
            int gn = bn + wn + j * 16 + col;
            if (gn >= Nn) continue;
            float bs = bias[gn];
            #pragma unroll
            for (int r = 0; r < 4; ++r) {
                int gm = gmb + r;
                if (gm >= M) continue;
                float v = acc[i][j][r] + bs;
                if (act == 1) v = gelu_tanh(v);
                if (resB) v += __bfloat162float(resB[(size_t)gm * Nn + gn]);
                outB[(size_t)gm * Nn + gn] = __float2bfloat16(v);
            }
        }
    }
}

// ---------- fused QKV GEMM: 64x64 tiles over N=1536, ping-pong staging ----------
__global__ __launch_bounds__(256, 2) void qkv_gemm(
    const __hip_bfloat16* __restrict__ A, const __hip_bfloat16* __restrict__ Wt,
    const float* __restrict__ bq, const float* __restrict__ bk, const float* __restrict__ bv,
    __hip_bfloat16* __restrict__ qb, __hip_bfloat16* __restrict__ kb,
    __hip_bfloat16* __restrict__ vt, int nbm, int nbn) {
    const int M = B * T, K = D;
    __shared__ __align__(16) __hip_bfloat16 As[2][64 * 32];
    __shared__ __align__(16) __hip_bfloat16 Bs[2][64 * 32];
    int id = blockIdx.x;
    int xcd = id & 7, slot = id >> 3;
    int bmb = xcd + 8 * (slot / nbn);
    int bnb = slot % nbn;
    if (bmb >= nbm) return;
    int bm = bmb * 64;
    int bn = bnb * 64;
    int tid = threadIdx.x;
    int lane = tid & 63;
    int wave = tid >> 6;
    int col = lane & 15;
    int quad = lane >> 4;
    int wm = (wave & 1) * 32;
    int wn = (wave >> 1) * 32;
    f32x4 acc[2][2];
    #pragma unroll
    for (int i = 0; i < 2; ++i)
        #pragma unroll
        for (int j = 0; j < 2; ++j) acc[i][j] = (f32x4){0.f, 0.f, 0.f, 0.f};

    auto stage = [&](int itk, int bufi) {
        int k0 = itk << 5;
        int cbase = wave * 64;
        int c = cbase + lane;
        int row = c >> 2;
        int g = (c & 3) ^ SWZM(row);
        int gm = bm + row; if (gm >= M) gm = M - 1;
        const __hip_bfloat16* ga = A + (size_t)gm * K + k0 + g * 8;
        __builtin_amdgcn_global_load_lds(
            (const __attribute__((address_space(1))) void*)ga,
            (__attribute__((address_space(3))) void*)(As[bufi] + (size_t)cbase * 8), 16, 0, 0);
        int gn = bn + row;
        const __hip_bfloat16* gb = Wt + (size_t)gn * K + k0 + g * 8;
        __builtin_amdgcn_global_load_lds(
            (const __attribute__((address_space(1))) void*)gb,
            (__attribute__((address_space(3))) void*)(Bs[bufi] + (size_t)cbase * 8), 16, 0, 0);
    };

    const int nIt = K >> 5;
    stage(0, 0);
    for (int itk = 0; itk < nIt; ++itk) {
        __syncthreads();
        if (itk + 1 < nIt) stage(itk + 1, (itk + 1) & 1);
        const __hip_bfloat16* Ac = As[itk & 1];
        const __hip_bfloat16* Bc = Bs[itk & 1];
        bf16x8 af[2], bfr[2];
        #pragma unroll
        for (int i = 0; i < 2; ++i) {
            int ra = wm + i * 16 + col;
            af[i] = *(const bf16x8*)(const void*)&Ac[(ra * 4 + (quad ^ SWZM(ra))) * 8];
        }
        #pragma unroll
        for (int j = 0; j < 2; ++j) {
            int rb = wn + j * 16 + col;
            bfr[j] = *(const bf16x8*)(const void*)&Bc[(rb * 4 + (quad ^ SWZM(rb))) * 8];
        }
        #pragma unroll
        for (int i = 0; i < 2; ++i)
            #pragma unroll
            for (int j = 0; j < 2; ++j)
                acc[i][j] = __builtin_amdgcn_mfma_f32_16x16x32_bf16(af[i], bfr[j], acc[i][j], 0, 0, 0);
    }
    int sel = bn >> 9;            // block-uniform: 0=Q 1=K 2=V
    const float* bias = sel == 0 ? bq : sel == 1 ? bk : bv;
    #pragma unroll
    for (int i = 0; i < 2; ++i) {
        int gmb = bm + wm + i * 16 + quad * 4;
        #pragma unroll
        for (int j = 0; j < 2; ++j) {
            int gn = bn + wn + j * 16 + col;
            int gl = gn & 511;
            float bs = bias[gl];
            #pragma unroll
            for (int r = 0; r < 4; ++r) {
                int gm = gmb + r;
                if (gm >= M) continue;
                float v = acc[i][j][r] + bs;
                if (sel == 0)      qb[(size_t)gm * 512 + gl] = __float2bfloat16(v);
                else if (sel == 1) kb[(size_t)gm * 512 + gl] = __float2bfloat16(v);
                else {
                    int bb = gm / T;
                    int tt = gm - bb * T;
                    vt[((size_t)bb * 512 + gl) * VTS + tt] = __float2bfloat16(v);
                }
            }
        }
    }
}

// ---------- flash-style MFMA attention, fixed exp shift (scores bounded) ----------
__global__ __launch_bounds__(256) void attn_flash_kernel(
    const __hip_bfloat16* __restrict__ qb, const __hip_bfloat16* __restrict__ kb,
    const __hip_bfloat16* __restrict__ vt, const __hip_bfloat16* __restrict__ gd,
    __hip_bfloat16* __restrict__ ctxb) {
    __shared__ __align__(16) __hip_bfloat16 Ks[64][72];
    __shared__ __align__(16) __hip_bfloat16 Vs[64][72];
    __shared__ __align__(16) __hip_bfloat16 Pw[4][16][72];
    __shared__ __align__(16) __hip_bfloat16 Gs[64][68];
    int bid = blockIdx.x;
    int sg = bid % 9;
    int h = (bid / 9) % H;
    int b = bid / (9 * H);
    int tid = threadIdx.x;
    int wave = tid >> 6, lane = tid & 63;
    int col = lane & 15, quad = lane >> 4;
    int q0b = sg * 64;
    int q0 = q0b + wave * 16;

    int qr = q0 + col; if (qr > T - 1) qr = T - 1;
    const __hip_bfloat16* qptr = qb + (size_t)(b * T + qr) * D + h * E + quad * 8;
    bf16x8 a0 = *(const bf16x8*)(const void*)qptr;
    bf16x8 a1 = *(const bf16x8*)(const void*)(qptr + 32);

    float S[4] = {0.f, 0.f, 0.f, 0.f};
    float G[4] = {0.f, 0.f, 0.f, 0.f};
    f32x4 o[4];
    #pragma unroll
    for (int j = 0; j < 4; ++j) o[j] = (f32x4){0.f, 0.f, 0.f, 0.f};

    const __hip_bfloat16* vbase = vt + (size_t)((b * H + h) * E) * VTS;

    for (int kc = 0; kc < NCHUNK; ++kc) {
        __syncthreads();
        #pragma unroll
        for (int i = 0; i < 2; ++i) {
            int idx = tid + i * 256;
            int r = idx >> 3, s = idx & 7;
            int kr = kc * 64 + r; int krc = kr > T - 1 ? T - 1 : kr;
            *(bf16x8*)(void*)&Ks[r][s * 8] =
                *(const bf16x8*)(const void*)(kb + (size_t)(b * T + krc) * D + h * E + s * 8);
            *(bf16x8*)(void*)&Vs[r][s * 8] =
                *(const bf16x8*)(const void*)(vbase + (size_t)r * VTS + kc * 64 + s * 8);
            bf16x8 gval;
            int grow = q0b + r;
            if (grow < N && kc < 8) {
                gval = *(const bf16x8*)(const void*)(gd + ((size_t)b * N + grow) * N + kc * 64 + s * 8);
            } else {
                gval = (bf16x8){0x3F00, 0x3F00, 0x3F00, 0x3F00, 0x3F00, 0x3F00, 0x3F00, 0x3F00};
            }
            *(bf16x8*)(void*)&Gs[r][s * 8] = gval;
        }
        __syncthreads();
        #pragma unroll
        for (int sub = 0; sub < 4; ++sub) {
            bf16x8 b0 = *(const bf16x8*)(const void*)&Ks[sub * 16 + col][quad * 8];
            bf16x8 b1 = *(const bf16x8*)(const void*)&Ks[sub * 16 + col][32 + quad * 8];
            f32x4 sc = (f32x4){0.f, 0.f, 0.f, 0.f};
            sc = __builtin_amdgcn_mfma_f32_16x16x32_bf16(a0, b0, sc, 0, 0, 0);
            sc = __builtin_amdgcn_mfma_f32_16x16x32_bf16(a1, b1, sc, 0, 0, 0);
            int key = kc * 64 + sub * 16 + col;
            #pragma unroll
            for (int r = 0; r < 4; ++r) {
                float v = sc[r] * 0.125f;
                if (key >= T) v = -1e30f;       // exp underflows to exactly 0
                float p = __expf(v);
                S[r] += p;
                float g = __bfloat162float(Gs[wave * 16 + quad * 4 + r][sub * 16 + col]);
                float t = p * g;
                G[r] += t;
                Pw[wave][quad * 4 + r][sub * 16 + col] = __float2bfloat16(t);
            }
        }
        #pragma unroll
        for (int ks = 0; ks < 2; ++ks) {
            bf16x8 pa = *(const bf16x8*)(const void*)&Pw[wave][col][ks * 32 + quad * 8];
            #pragma unroll
            for (int j = 0; j < 4; ++j) {
                bf16x8 bv = *(const bf16x8*)(const void*)&Vs[j * 16 + col][ks * 32 + quad * 8];
                o[j] = __builtin_amdgcn_mfma_f32_16x16x32_bf16(pa, bv, o[j], 0, 0, 0);
            }
        }
    }
    #pragma unroll
    for (int r = 0; r < 4; ++r) {
        #pragma unroll
        for (int d = 1; d < 16; d <<= 1) {
            S[r] += __shfl_xor(S[r], d, 64);
            G[r] += __shfl_xor(G[r], d, 64);
        }
    }
    float inv[4];
    #pragma unroll
    for (int r = 0; r < 4; ++r) inv[r] = 1.f / (G[r] + 1e-6f * S[r]);
    #pragma unroll
    for (int j = 0; j < 4; ++j)
        #pragma unroll
        for (int r = 0; r < 4; ++r) {
            int row = q0 + quad * 4 + r;
            if (row < T)
                ctxb[(size_t)(b * T + row) * D + h * E + j * 16 + col] =
                    __float2bfloat16(o[j][r] * inv[r]);
        }
}

// ---------- layernorm: bf16 in-place, wave-per-row, no barriers ----------
__global__ __launch_bounds__(256) void ln_kernel(__hip_bfloat16* __restrict__ xr,
                                                 const float* __restrict__ g,
                                                 const float* __restrict__ bb) {
    int row = blockIdx.x * 4 + (threadIdx.x >> 6);
    int lane = threadIdx.x & 63;
    __hip_bfloat16* base = xr + (size_t)row * D + lane * 8;
    __align__(16) __hip_bfloat16 u[8];
    *(bf16x8*)(void*)u = *(const bf16x8*)(const void*)base;
    float v[8];
    float s = 0.f, ss = 0.f;
    #pragma unroll
    for (int i = 0; i < 8; ++i) {
        v[i] = __bfloat162float(u[i]);
        s += v[i];
        ss += v[i] * v[i];
    }
    #pragma unroll
    for (int d = 1; d < 64; d <<= 1) {
        s += __shfl_xor(s, d, 64);
        ss += __shfl_xor(ss, d, 64);
    }
    float m = s * (1.f / (float)D);
    float var = ss * (1.f / (float)D) - m * m;
    float rstd = rsqrtf(fmaxf(var, 0.f) + 1e-5f);
    float4 g0 = *(const float4*)(g + lane * 8);
    float4 g1 = *(const float4*)(g + lane * 8 + 4);
    float4 b0 = *(const float4*)(bb + lane * 8);
    float4 b1 = *(const float4*)(bb + lane * 8 + 4);
    float gg[8] = {g0.x, g0.y, g0.z, g0.w, g1.x, g1.y, g1.z, g1.w};
    float bz[8] = {b0.x, b0.y, b0.z, b0.w, b1.x, b1.y, b1.z, b1.w};
    __align__(16) __hip_bfloat16 ot[8];
    #pragma unroll
    for (int i = 0; i < 8; ++i)
        ot[i] = __float2bfloat16((v[i] - m) * rstd * gg[i] + bz[i]);
    *(bf16x8*)(void*)base = *(const bf16x8*)(const void*)ot;
}

// ---------- proj GEMM with fused transpose + RevIN inverse epilogue ----------
__global__ __launch_bounds__(256, 2) void proj_revin_gemm(
    const __hip_bfloat16* __restrict__ A, const __hip_bfloat16* __restrict__ Wt,
    const float* __restrict__ pb, const float* __restrict__ beta,
    const float* __restrict__ gamma, const float* __restrict__ mean,
    const float* __restrict__ stdv, float* __restrict__ out, int nbm, int nbn) {
    const int M = B * T, K = D, Nn = PRED;
    __shared__ __align__(16) __hip_bfloat16 As[64 * 32];
    __shared__ __align__(16) __hip_bfloat16 Bs[64 * 32];
    int id = blockIdx.x;
    int xcd = id & 7, slot = id >> 3;
    int bmb = xcd + 8 * (slot / nbn);
    int bnb = slot % nbn;
    if (bmb >= nbm) return;
    int bm = bmb * 64;
    int bn = bnb * 64;
    int tid = threadIdx.x;
    int lane = tid & 63;
    int wave = tid >> 6;
    int col = lane & 15;
    int quad = lane >> 4;
    int wm = (wave & 1) * 32;
    int wn = (wave >> 1) * 32;
    f32x4 acc[2][2];
    #pragma unroll
    for (int i = 0; i < 2; ++i)
        #pragma unroll
        for (int j = 0; j < 2; ++j) acc[i][j] = (f32x4){0.f, 0.f, 0.f, 0.f};

    for (int k0 = 0; k0 < K; k0 += 32) {
        {
            int cbase = wave * 64;
            int c = cbase + lane;
            int row = c >> 2;
            int g = (c & 3) ^ SWZM(row);
            int gm = bm + row; if (gm >= M) gm = M - 1;
            const __hip_bfloat16* ga = A + (size_t)gm * K + k0 + g * 8;
            __builtin_amdgcn_global_load_lds(
                (const __attribute__((address_space(1))) void*)ga,
                (__attribute__((address_space(3))) void*)(As + (size_t)cbase * 8), 16, 0, 0);
            int gn = bn + row; if (gn >= Nn) gn = Nn - 1;
            const __hip_bfloat16* gb = Wt + (size_t)gn * K + k0 + g * 8;
            __builtin_amdgcn_global_load_lds(
                (const __attribute__((address_space(1))) void*)gb,
                (__attribute__((address_space(3))) void*)(Bs + (size_t)cbase * 8), 16, 0, 0);
        }
        __syncthreads();
        bf16x8 af[2], bfr[2];
        #pragma unroll
        for (int i = 0; i < 2; ++i) {
            int ra = wm + i * 16 + col;
            af[i] = *(const bf16x8*)(const void*)&As[(ra * 4 + (quad ^ SWZM(ra))) * 8];
        }
        #pragma unroll
        for (int j = 0; j < 2; ++j) {
            int rb = wn + j * 16 + col;
            bfr[j] = *(const bf16x8*)(const void*)&Bs[(rb * 4 + (quad ^ SWZM(rb))) * 8];
        }
        #pragma unroll
        for (int i = 0; i < 2; ++i)
            #pragma unroll
            for (int j = 0; j < 2; ++j)
                acc[i][j] = __builtin_amdgcn_mfma_f32_16x16x32_bf16(af[i], bfr[j], acc[i][j], 0, 0, 0);
        __syncthreads();
    }
    #pragma unroll
    for (int i = 0; i < 2; ++i) {
        int gmb = bm + wm + i * 16 + quad * 4;
        int b = gmb / T;
        int n0 = gmb - b * T;
        #pragma unroll
        for (int j = 0; j < 2; ++j) {
            int gn = bn + wn + j * 16 + col;   // prediction index p
            if (gn >= PRED) continue;
            float bs = pb[gn];
            #pragma unroll
            for (int r = 0; r < 4; ++r) {
                int gm = gmb + r;
                if (gm >= M) continue;
                int n = n0 + r;
                if (n >= N) continue;          // mark-token rows dropped
                int bn_ = b * N + n;
                float v = acc[i][j][r] + bs;
                out[((size_t)b * PRED + gn) * N + n] =
                    (v - beta[n]) * (stdv[bn_] / (gamma[n] + 1e-5f)) + mean[bn_];
            }
        }
    }
}

static inline int swz_grid(int nbm, int nbn) { return 8 * ((nbm + 7) / 8) * nbn; }

extern "C" void kernel_launch(void* const* d_in, const int* in_sizes, int n_in,
                              void* d_out, int out_size, void* d_ws, size_t ws_size,
                              hipStream_t stream) {
    const float* x_enc  = (const float*)d_in[0];
    const float* x_mark = (const float*)d_in[1];
    const float* gamma  = (const float*)d_in[4];
    const float* beta   = (const float*)d_in[5];
    const float* tp_w1  = (const float*)d_in[6];
    const float* tp_b1  = (const float*)d_in[7];
    const float* tp_w2  = (const float*)d_in[8];
    const float* tp_b2  = (const float*)d_in[9];
    const float* emb_w  = (const float*)d_in[10];
    const float* emb_b  = (const float*)d_in[11];
    const float* wq = (const float*)d_in[12];
    const float* bq = (const float*)d_in[13];
    const float* wk = (const float*)d_in[14];
    const float* bk = (const float*)d_in[15];
    const float* wv = (const float*)d_in[16];
    const float* bv = (const float*)d_in[17];
    const float* wo = (const float*)d_in[18];
    const float* bo = (const float*)d_in[19];
    const float* w1 = (const float*)d_in[20];
    const float* b1 = (const float*)d_in[21];
    const float* w2 = (const float*)d_in[22];
    const float* b2 = (const float*)d_in[23];
    const float* ln1g = (const float*)d_in[24];
    const float* ln1b = (const float*)d_in[25];
    const float* ln2g = (const float*)d_in[26];
    const float* ln2b = (const float*)d_in[27];
    const float* normg = (const float*)d_in[28];
    const float* normb = (const float*)d_in[29];
    const float* proj_w = (const float*)d_in[30];
    const float* proj_b = (const float*)d_in[31];

    char* ws = (char*)d_ws;
    float* mean = (float*)(ws + WS_MEAN);
    float* stdv = (float*)(ws + WS_STD);
    __hip_bfloat16* gd  = (__hip_bfloat16*)(ws + WS_GD);
    __hip_bfloat16* R   = (__hip_bfloat16*)(ws + WS_X);   // bf16 residual stream
    __hip_bfloat16* ctxb = (__hip_bfloat16*)(ws + WS_XB);
    __hip_bfloat16* wts = (__hip_bfloat16*)(ws + WS_WTS);
    __hip_bfloat16* qbuf = (__hip_bfloat16*)(ws + WS_QB);
    __hip_bfloat16* kbuf = (__hip_bfloat16*)(ws + WS_KB);
    __hip_bfloat16* vt   = (__hip_bfloat16*)(ws + WS_VT);
    float* xt  = (float*)(ws + WS_KB);
    __hip_bfloat16* ntb = (__hip_bfloat16*)(ws + WS_VT);
    __hip_bfloat16* tokb = (__hip_bfloat16*)(ws + WS_QB);
    __hip_bfloat16* ffnb = (__hip_bfloat16*)(ws + WS_QB);

    revin_stats_kernel<<<(B * N + 255) / 256, 256, 0, stream>>>(x_enc, mean, stdv);
    norm_transpose_kernel<<<(B * N * L + 255) / 256, 256, 0, stream>>>(x_enc, mean, stdv, gamma, beta,
                                                                       xt, tokb);
    build_mark_kernel<<<(B * NMARK * L + 255) / 256, 256, 0, stream>>>(x_mark, tokb);
    trend_nt_kernel<<<B * N, 128, 0, stream>>>(xt, tp_w1, tp_b1, tp_w2, tp_b2, ntb);
    guide_mfma_kernel<<<B * 64, 256, 0, stream>>>(ntb, gd);
    // vt aliases ntb: stale bytes as bf16 can be NaN in pad tokens; 0*NaN=NaN
    // in the PV MFMA. Zero once per launch (layer GEMMs rewrite tokens 0..515).
    hipMemsetAsync(vt, 0, VT_BYTES, stream);
    wconv_kernel<<<6240, 256, 0, stream>>>(wq, wk, wv, wo, w1, w2, emb_w, proj_w, wts);

    const int M = B * T;                   // 8256
    const int NBM64 = (M + 63) / 64;       // 129
    const int NBM128 = (M + 127) / 128;    // 65
    mfma_gemm_t<64, 64><<<swz_grid(NBM64, 8), 256, 0, stream>>>(
        tokb, wts + WT_EMB, emb_b, nullptr, R, M, D, L, 0, NBM64, 8);
    for (int i = 0; i < 2; ++i) {
        const __hip_bfloat16* qkvT = wts + WT_QKV + (size_t)i * 1536 * 512;
        const __hip_bfloat16* woT  = wts + WT_WO + (size_t)i * D * D;
        qkv_gemm<<<swz_grid(NBM64, 24), 256, 0, stream>>>(
            R, qkvT, bq + i * D, bk + i * D, bv + i * D, qbuf, kbuf, vt, NBM64, 24);
        attn_flash_kernel<<<B * H * 9, 256, 0, stream>>>(qbuf, kbuf, vt, gd, ctxb);
        mfma_gemm_t<64, 64><<<swz_grid(NBM64, 8), 256, 0, stream>>>(
            ctxb, woT, bo + i * D, R, R, M, D, D, 0, NBM64, 8);
        ln_kernel<<<M / 4, 256, 0, stream>>>(R, ln1g + i * D, ln1b + i * D);
        mfma_gemm_t<128, 128><<<swz_grid(NBM128, 16), 256, 0, stream>>>(
            R, wts + WT_W1 + (size_t)i * DFF * D, b1 + i * DFF, nullptr,
            ffnb, M, DFF, D, 1, NBM128, 16);
        mfma_gemm_t<64, 64><<<swz_grid(NBM64, 8), 256, 0, stream>>>(
            ffnb, wts + WT_W2 + (size_t)i * DFF * D, b2 + i * D, R, R,
            M, D, DFF, 0, NBM64, 8);
        ln_kernel<<<M / 4, 256, 0, stream>>>(R, ln2g + i * D, ln2b + i * D);
    }
    ln_kernel<<<M / 4, 256, 0, stream>>>(R, normg, normb);
    proj_revin_gemm<<<swz_grid(NBM64, 2), 256, 0, stream>>>(
        R, wts + WT_PROJ, proj_b, beta, gamma, mean, stdv, (float*)d_out, NBM64, 2);
}

// Round 14
// 611.506 us; speedup vs baseline: 1.0409x; 1.0409x over previous
//
#include <hip/hip_runtime.h>
#include <hip/hip_bf16.h>
#include <math.h>

#define B 16
#define L 96
#define N 512
#define D 512
#define H 8
#define E 64
#define DFF 2048
#define T 516
#define PRED 96
#define NMARK 4
#define VTS 576    // vt row stride (keys, padded from 516 to 9*64)
#define NCHUNK 9   // key chunks of 64

typedef __attribute__((ext_vector_type(8))) short bf16x8;
typedef __attribute__((ext_vector_type(4))) float f32x4;

// ---- workspace layout (BYTE offsets). Total 80,412,672 B ----
#define WS_MEAN 0              // f32 [B,N]
#define WS_STD  32768          // f32 [B,N]
#define WS_GD   65536          // bf16 [B,N,N] = 8,388,608 B
#define WS_X    8454144        // bf16 [B,T,D] residual stream R
#define WS_XB   25362432       // bf16 [B,T,D] ctxb
#define WS_WTS  33816576       // bf16 transposed weights, 12,779,520 B
#define WS_QB   46596096       // bf16 [B,T,D]; also tokb(bf16), ffn base
#define WS_KB   55050240       // bf16 [B,T,D]; also xt(f32)
#define WS_VT   63504384       // bf16 [B,H,64,VTS] = 9,437,184 B; also ntb(bf16)
#define VT_BYTES 9437184
// ffnb = WS_QB .. WS_QB + 8256*2048*2 = 80,412,672 (spans qb,kb,vt; time-disjoint)

// weight-arena element offsets (bf16 elements from WS_WTS)
#define WT_QKV  0u          // [2][1536][512]: rows 0..511 Q, 512..1023 K, 1024..1535 V
#define WT_WO   1572864u    // [2][512][512]
#define WT_W1   2097152u    // [2][2048][512]
#define WT_W2   4194304u    // [2][512][2048]
#define WT_EMB  6291456u    // [512][96]
#define WT_PROJ 6340608u    // [96][512]

// ---------- RevIN stats ----------
__global__ void revin_stats_kernel(const float* __restrict__ x, float* __restrict__ mean,
                                   float* __restrict__ stdv) {
    int i = blockIdx.x * blockDim.x + threadIdx.x;
    if (i >= B * N) return;
    int b = i >> 9;
    int n = i & (N - 1);
    const float* p = x + (size_t)b * L * N + n;
    float s = 0.f, ss = 0.f;
    for (int l = 0; l < L; ++l) {
        float v = p[(size_t)l * N];
        s += v; ss += v * v;
    }
    float m = s / (float)L;
    float var = ss / (float)L - m * m;
    mean[i] = m;
    stdv[i] = sqrtf(fmaxf(var, 0.f) + 1e-5f);
}

// ---------- normalize + transpose: xt[b,n,l] (f32) + tokb[b,n,l] (bf16) ----------
__global__ void norm_transpose_kernel(const float* __restrict__ x, const float* __restrict__ mean,
                                      const float* __restrict__ stdv, const float* __restrict__ gamma,
                                      const float* __restrict__ beta, float* __restrict__ xt,
                                      __hip_bfloat16* __restrict__ tokb) {
    int idx = blockIdx.x * blockDim.x + threadIdx.x;
    if (idx >= B * N * L) return;
    int l = idx % L;
    int n = (idx / L) % N;
    int b = idx / (L * N);
    float v = x[((size_t)b * L + l) * N + n];
    int bn = b * N + n;
    float o = (v - mean[bn]) / stdv[bn] * gamma[n] + beta[n];
    xt[idx] = o;
    tokb[((size_t)b * T + n) * L + l] = __float2bfloat16(o);
}

// ---------- fill token mark rows N..T-1 ----------
__global__ void build_mark_kernel(const float* __restrict__ xmark, __hip_bfloat16* __restrict__ tok) {
    int idx = blockIdx.x * blockDim.x + threadIdx.x;
    if (idx >= B * NMARK * L) return;
    int l = idx % L;
    int t = (idx / L) % NMARK;
    int b = idx / (L * NMARK);
    tok[((size_t)b * T + N + t) * L + l] =
        __float2bfloat16(xmark[((size_t)b * L + l) * NMARK + t]);
}

// ---------- trend + normalized trend rows ntb[b,n,l] (bf16) ----------
__global__ void trend_nt_kernel(const float* __restrict__ xt, const float* __restrict__ tp_w1,
                                const float* __restrict__ tp_b1, const float* __restrict__ tp_w2,
                                const float* __restrict__ tp_b2, __hip_bfloat16* __restrict__ ntb) {
    int bn = blockIdx.x;
    __shared__ float xr[96];
    __shared__ float P[97];
    __shared__ float wt[4];
    __shared__ float tr[96];
    __shared__ float nrm;
    int tid = threadIdx.x;
    if (tid < 96) xr[tid] = xt[(size_t)bn * 96 + tid];
    __syncthreads();
    if (tid == 0) {
        float s = 0.f, ss = 0.f;
        P[0] = 0.f;
        for (int l = 0; l < 96; ++l) { s += xr[l]; P[l + 1] = s; ss += xr[l] * xr[l]; }
        float m = s / 96.f;
        float var = ss / 96.f - m * m;
        float sd = sqrtf(fmaxf(var, 0.f) + 1e-6f);
        float h[16];
        for (int j = 0; j < 16; ++j) {
            float t = m * tp_w1[j] + sd * tp_w1[16 + j] + tp_b1[j];
            h[j] = fmaxf(t, 0.f);
        }
        float lg[4];
        for (int w = 0; w < 4; ++w) {
            float t = tp_b2[w];
            for (int j = 0; j < 16; ++j) t += h[j] * tp_w2[j * 4 + w];
            lg[w] = t;
        }
        float mx = fmaxf(fmaxf(lg[0], lg[1]), fmaxf(lg[2], lg[3]));
        float es = 0.f;
        for (int w = 0; w < 4; ++w) { lg[w] = expf(lg[w] - mx); es += lg[w]; }
        for (int w = 0; w < 4; ++w) wt[w] = lg[w] / es;
    }
    __syncthreads();
    const int WS[4] = {4, 8, 12, 24};
    if (tid < 96) {
        int l = tid;
        float t = 0.f;
        for (int wi = 0; wi < 4; ++wi) {
            int w = WS[wi];
            int lo = l - w + 1;
            float s;
            if (lo >= 0) s = P[l + 1] - P[lo];
            else         s = P[l + 1] - P[0] + (float)(-lo) * xr[0];
            t += (s / (float)w) * wt[wi];
        }
        tr[l] = t;
    }
    __syncthreads();
    if (tid == 0) {
        float s = 0.f;
        for (int l = 0; l < 96; ++l) s += tr[l] * tr[l];
        nrm = fmaxf(sqrtf(s), 1e-12f);
    }
    __syncthreads();
    if (tid < 96) ntb[(size_t)bn * 96 + tid] = __float2bfloat16(tr[tid] / nrm);
}

// XOR swizzle (BK=32): LDS slot sl of row holds global segment sl^((row>>1)&3)
#define SWZM(row) (((row) >> 1) & 3)

// ---------- guidance via MFMA: gd = sigmoid(nt @ nt^T), per batch ----------
__global__ __launch_bounds__(256, 2) void guide_mfma_kernel(
    const __hip_bfloat16* __restrict__ nt, __hip_bfloat16* __restrict__ gd) {
    __shared__ __align__(16) __hip_bfloat16 As[64 * 32];
    __shared__ __align__(16) __hip_bfloat16 Bs[64 * 32];
    int id = blockIdx.x;
    int b = id >> 6;
    int tile = id & 63;
    int bm = (tile >> 3) * 64;
    int bn = (tile & 7) * 64;
    const __hip_bfloat16* base = nt + (size_t)b * N * 96;
    int tid = threadIdx.x;
    int lane = tid & 63;
    int wave = tid >> 6;
    int col = lane & 15;
    int quad = lane >> 4;
    int wm = (wave & 1) * 32;
    int wn = (wave >> 1) * 32;
    f32x4 acc[2][2];
    #pragma unroll
    for (int i = 0; i < 2; ++i)
        #pragma unroll
        for (int j = 0; j < 2; ++j) acc[i][j] = (f32x4){0.f, 0.f, 0.f, 0.f};

    #pragma unroll
    for (int k0 = 0; k0 < 96; k0 += 32) {
        {
            int cbase = wave * 64;
            int c = cbase + lane;
            int row = c >> 2;
            int g = (c & 3) ^ SWZM(row);
            const __hip_bfloat16* ga = base + (size_t)(bm + row) * 96 + k0 + g * 8;
            __builtin_amdgcn_global_load_lds(
                (const __attribute__((address_space(1))) void*)ga,
                (__attribute__((address_space(3))) void*)(As + (size_t)cbase * 8), 16, 0, 0);
            const __hip_bfloat16* gb = base + (size_t)(bn + row) * 96 + k0 + g * 8;
            __builtin_amdgcn_global_load_lds(
                (const __attribute__((address_space(1))) void*)gb,
                (__attribute__((address_space(3))) void*)(Bs + (size_t)cbase * 8), 16, 0, 0);
        }
        __syncthreads();
        bf16x8 af[2], bfr[2];
        #pragma unroll
        for (int i = 0; i < 2; ++i) {
            int ra = wm + i * 16 + col;
            af[i] = *(const bf16x8*)(const void*)&As[(ra * 4 + (quad ^ SWZM(ra))) * 8];
        }
        #pragma unroll
        for (int j = 0; j < 2; ++j) {
            int rb = wn + j * 16 + col;
            bfr[j] = *(const bf16x8*)(const void*)&Bs[(rb * 4 + (quad ^ SWZM(rb))) * 8];
        }
        #pragma unroll
        for (int i = 0; i < 2; ++i)
            #pragma unroll
            for (int j = 0; j < 2; ++j)
                acc[i][j] = __builtin_amdgcn_mfma_f32_16x16x32_bf16(af[i], bfr[j], acc[i][j], 0, 0, 0);
        __syncthreads();
    }
    #pragma unroll
    for (int i = 0; i < 2; ++i) {
        int gmb = bm + wm + i * 16 + quad * 4;
        #pragma unroll
        for (int j = 0; j < 2; ++j) {
            int gn = bn + wn + j * 16 + col;
            #pragma unroll
            for (int r = 0; r < 4; ++r) {
                int gm = gmb + r;
                float sig = __builtin_amdgcn_rcpf(1.f + __expf(-acc[i][j][r]));
                gd[((size_t)b * N + gm) * N + gn] = __float2bfloat16(sig);
            }
        }
    }
}

// ---------- weight transpose+convert: fp32 [K,N] -> bf16 [N,K] ----------
__global__ void wconv_kernel(const float* __restrict__ wq, const float* __restrict__ wk,
                             const float* __restrict__ wv, const float* __restrict__ wo,
                             const float* __restrict__ w1, const float* __restrict__ w2,
                             const float* __restrict__ emb, const float* __restrict__ proj,
                             __hip_bfloat16* __restrict__ wts) {
    int bid = blockIdx.x;
    const float* src; __hip_bfloat16* dst; int K, Nn, tloc;
    if (bid < 2048) {
        int seg = bid >> 9;          // 0=wq 1=wk 2=wv 3=wo
        int t = bid & 511;
        int layer = t >> 8;
        tloc = t & 255;
        K = 512; Nn = 512;
        const float* bases[4] = {wq, wk, wv, wo};
        src = bases[seg] + (size_t)layer * 512 * 512;
        if (seg < 3)
            dst = wts + WT_QKV + (size_t)layer * 1536 * 512 + (size_t)seg * 512 * 512;
        else
            dst = wts + WT_WO + (size_t)layer * 512 * 512;
    } else if (bid < 4096) {
        int t = bid - 2048;
        int layer = t >> 10;
        tloc = t & 1023;
        K = 512; Nn = 2048;
        src = w1 + (size_t)layer * 512 * 2048;
        dst = wts + WT_W1 + (size_t)layer * 2048 * 512;
    } else if (bid < 6144) {
        int t = bid - 4096;
        int layer = t >> 10;
        tloc = t & 1023;
        K = 2048; Nn = 512;
        src = w2 + (size_t)layer * 2048 * 512;
        dst = wts + WT_W2 + (size_t)layer * 512 * 2048;
    } else if (bid < 6192) {
        tloc = bid - 6144;
        K = 96; Nn = 512;
        src = emb; dst = wts + WT_EMB;
    } else {
        tloc = bid - 6192;
        K = 512; Nn = 96;
        src = proj; dst = wts + WT_PROJ;
    }
    int ntile = Nn >> 5;
    int tk = tloc / ntile, tn = tloc % ntile;
    int k0 = tk * 32, n0 = tn * 32;
    __shared__ float ld[32][33];
    int tid = threadIdx.x;
    for (int i = tid; i < 1024; i += 256) {
        int r = i >> 5, c = i & 31;
        ld[r][c] = src[(size_t)(k0 + r) * Nn + n0 + c];
    }
    __syncthreads();
    for (int i = tid; i < 1024; i += 256) {
        int r = i >> 5, c = i & 31;
        dst[(size_t)(n0 + r) * K + k0 + c] = __float2bfloat16(ld[c][r]);
    }
}

__device__ __forceinline__ float gelu_tanh(float v) {
    // (1+tanh z)/2 == sigmoid(2z): mathematically identical, 2 transcendentals
    float y = 1.5957691216057308f * v * fmaf(0.044715f, v * v, 1.f);
    float e = __expf(-y);
    return v * __builtin_amdgcn_rcpf(1.f + e);
}

// ---------- templated MFMA bf16 GEMM: TM x TN tile, BK=32, 4 waves ----------
// Ping-pong LDS staging; 1-D grid XCD-swizzled.
template<int TM, int TN>
__global__ __launch_bounds__(256, 2) void mfma_gemm_t(
    const __hip_bfloat16* __restrict__ A, const __hip_bfloat16* __restrict__ Wt,
    const float* __restrict__ bias, const __hip_bfloat16* __restrict__ resB,
    __hip_bfloat16* __restrict__ outB,
    int M, int Nn, int K, int act, int nbm, int nbn) {
    constexpr int WM = TM / 2, WN = TN / 2;
    constexpr int FI = WM / 16, FJ = WN / 16;
    __shared__ __align__(16) __hip_bfloat16 As[2][TM * 32];
    __shared__ __align__(16) __hip_bfloat16 Bs[2][TN * 32];
    int id = blockIdx.x;
    int xcd = id & 7, slot = id >> 3;
    int bmb = xcd + 8 * (slot / nbn);
    int bnb = slot % nbn;
    if (bmb >= nbm) return;
    int bm = bmb * TM;
    int bn = bnb * TN;
    int tid = threadIdx.x;
    int lane = tid & 63;
    int wave = tid >> 6;
    int col = lane & 15;
    int quad = lane >> 4;
    int wm = (wave & 1) * WM;
    int wn = (wave >> 1) * WN;
    f32x4 acc[FI][FJ];
    #pragma unroll
    for (int i = 0; i < FI; ++i)
        #pragma unroll
        for (int j = 0; j < FJ; ++j) acc[i][j] = (f32x4){0.f, 0.f, 0.f, 0.f};

    auto stage = [&](int itk, int bufi) {
        int k0 = itk << 5;
        #pragma unroll
        for (int it = 0; it < TM / 64; ++it) {
            int cbase = it * 256 + wave * 64;
            int c = cbase + lane;
            int row = c >> 2;
            int g = (c & 3) ^ SWZM(row);
            int gm = bm + row; if (gm >= M) gm = M - 1;
            const __hip_bfloat16* ga = A + (size_t)gm * K + k0 + g * 8;
            __builtin_amdgcn_global_load_lds(
                (const __attribute__((address_space(1))) void*)ga,
                (__attribute__((address_space(3))) void*)(As[bufi] + (size_t)cbase * 8), 16, 0, 0);
        }
        #pragma unroll
        for (int it = 0; it < TN / 64; ++it) {
            int cbase = it * 256 + wave * 64;
            int c = cbase + lane;
            int row = c >> 2;
            int g = (c & 3) ^ SWZM(row);
            int gn = bn + row; if (gn >= Nn) gn = Nn - 1;
            const __hip_bfloat16* gb = Wt + (size_t)gn * K + k0 + g * 8;
            __builtin_amdgcn_global_load_lds(
                (const __attribute__((address_space(1))) void*)gb,
                (__attribute__((address_space(3))) void*)(Bs[bufi] + (size_t)cbase * 8), 16, 0, 0);
        }
    };

    const int nIt = K >> 5;
    stage(0, 0);
    for (int itk = 0; itk < nIt; ++itk) {
        __syncthreads();   // drains this iter's staged loads; protects buffer reuse
        if (itk + 1 < nIt) stage(itk + 1, (itk + 1) & 1);
        const __hip_bfloat16* Ac = As[itk & 1];
        const __hip_bfloat16* Bc = Bs[itk & 1];
        bf16x8 af[FI], bfr[FJ];
        #pragma unroll
        for (int i = 0; i < FI; ++i) {
            int ra = wm + i * 16 + col;
            af[i] = *(const bf16x8*)(const void*)&Ac[(ra * 4 + (quad ^ SWZM(ra))) * 8];
        }
        #pragma unroll
        for (int j = 0; j < FJ; ++j) {
            int rb = wn + j * 16 + col;
            bfr[j] = *(const bf16x8*)(const void*)&Bc[(rb * 4 + (quad ^ SWZM(rb))) * 8];
        }
        #pragma unroll
        for (int i = 0; i < FI; ++i)
            #pragma unroll
            for (int j = 0; j < FJ; ++j)
                acc[i][j] = __builtin_amdgcn_mfma_f32_16x16x32_bf16(af[i], bfr[j], acc[i][j], 0, 0, 0);
    }
    #pragma unroll
    for (int i = 0; i < FI; ++i) {
        int gmb = bm + wm + i * 16 + quad * 4;
        #pragma unroll
        for (int j = 0; j < FJ; ++j) {
            int gn = bn + wn + j * 16 + col;
            if (gn >= Nn) continue;
            float bs = bias[gn];
            #pragma unroll
            for (int r = 0; r < 4; ++r) {
                int gm = gmb + r;
                if (gm >= M) continue;
                float v = acc[i][j][r] + bs;
                if (act == 1) v = gelu_tanh(v);
                if (resB) v += __bfloat162float(resB[(size_t)gm * Nn + gn]);
                outB[(size_t)gm * Nn + gn] = __float2bfloat16(v);
            }
        }
    }
}

// ---------- fused QKV GEMM: 64x64 tiles over N=1536, ping-pong staging ----------
__global__ __launch_bounds__(256, 2) void qkv_gemm(
    const __hip_bfloat16* __restrict__ A, const __hip_bfloat16* __restrict__ Wt,
    const float* __restrict__ bq, const float* __restrict__ bk, const float* __restrict__ bv,
    __hip_bfloat16* __restrict__ qb, __hip_bfloat16* __restrict__ kb,
    __hip_bfloat16* __restrict__ vt, int nbm, int nbn) {
    const int M = B * T, K = D;
    __shared__ __align__(16) __hip_bfloat16 As[2][64 * 32];
    __shared__ __align__(16) __hip_bfloat16 Bs[2][64 * 32];
    int id = blockIdx.x;
    int xcd = id & 7, slot = id >> 3;
    int bmb = xcd + 8 * (slot / nbn);
    int bnb = slot % nbn;
    if (bmb >= nbm) return;
    int bm = bmb * 64;
    int bn = bnb * 64;
    int tid = threadIdx.x;
    int lane = tid & 63;
    int wave = tid >> 6;
    int col = lane & 15;
    int quad = lane >> 4;
    int wm = (wave & 1) * 32;
    int wn = (wave >> 1) * 32;
    f32x4 acc[2][2];
    #pragma unroll
    for (int i = 0; i < 2; ++i)
        #pragma unroll
        for (int j = 0; j < 2; ++j) acc[i][j] = (f32x4){0.f, 0.f, 0.f, 0.f};

    auto stage = [&](int itk, int bufi) {
        int k0 = itk << 5;
        int cbase = wave * 64;
        int c = cbase + lane;
        int row = c >> 2;
        int g = (c & 3) ^ SWZM(row);
        int gm = bm + row; if (gm >= M) gm = M - 1;
        const __hip_bfloat16* ga = A + (size_t)gm * K + k0 + g * 8;
        __builtin_amdgcn_global_load_lds(
            (const __attribute__((address_space(1))) void*)ga,
            (__attribute__((address_space(3))) void*)(As[bufi] + (size_t)cbase * 8), 16, 0, 0);
        int gn = bn + row;
        const __hip_bfloat16* gb = Wt + (size_t)gn * K + k0 + g * 8;
        __builtin_amdgcn_global_load_lds(
            (const __attribute__((address_space(1))) void*)gb,
            (__attribute__((address_space(3))) void*)(Bs[bufi] + (size_t)cbase * 8), 16, 0, 0);
    };

    const int nIt = K >> 5;
    stage(0, 0);
    for (int itk = 0; itk < nIt; ++itk) {
        __syncthreads();
        if (itk + 1 < nIt) stage(itk + 1, (itk + 1) & 1);
        const __hip_bfloat16* Ac = As[itk & 1];
        const __hip_bfloat16* Bc = Bs[itk & 1];
        bf16x8 af[2], bfr[2];
        #pragma unroll
        for (int i = 0; i < 2; ++i) {
            int ra = wm + i * 16 + col;
            af[i] = *(const bf16x8*)(const void*)&Ac[(ra * 4 + (quad ^ SWZM(ra))) * 8];
        }
        #pragma unroll
        for (int j = 0; j < 2; ++j) {
            int rb = wn + j * 16 + col;
            bfr[j] = *(const bf16x8*)(const void*)&Bc[(rb * 4 + (quad ^ SWZM(rb))) * 8];
        }
        #pragma unroll
        for (int i = 0; i < 2; ++i)
            #pragma unroll
            for (int j = 0; j < 2; ++j)
                acc[i][j] = __builtin_amdgcn_mfma_f32_16x16x32_bf16(af[i], bfr[j], acc[i][j], 0, 0, 0);
    }
    int sel = bn >> 9;            // block-uniform: 0=Q 1=K 2=V
    const float* bias = sel == 0 ? bq : sel == 1 ? bk : bv;
    #pragma unroll
    for (int i = 0; i < 2; ++i) {
        int gmb = bm + wm + i * 16 + quad * 4;
        #pragma unroll
        for (int j = 0; j < 2; ++j) {
            int gn = bn + wn + j * 16 + col;
            int gl = gn & 511;
            float bs = bias[gl];
            #pragma unroll
            for (int r = 0; r < 4; ++r) {
                int gm = gmb + r;
                if (gm >= M) continue;
                float v = acc[i][j][r] + bs;
                if (sel == 0)      qb[(size_t)gm * 512 + gl] = __float2bfloat16(v);
                else if (sel == 1) kb[(size_t)gm * 512 + gl] = __float2bfloat16(v);
                else {
                    int bb = gm / T;
                    int tt = gm - bb * T;
                    vt[((size_t)bb * 512 + gl) * VTS + tt] = __float2bfloat16(v);
                }
            }
        }
    }
}

// ---------- flash-style MFMA attention, XCD-swizzled block order ----------
// xcd = id&7 owns 16 consecutive (b,h) pairs (= 2 batches): all 9 sg-strips of
// a pair (which re-read identical K/V) plus all 8 heads of a batch (which
// re-read identical gd rows) co-locate on one XCD's L2.
__global__ __launch_bounds__(256) void attn_flash_kernel(
    const __hip_bfloat16* __restrict__ qb, const __hip_bfloat16* __restrict__ kb,
    const __hip_bfloat16* __restrict__ vt, const __hip_bfloat16* __restrict__ gd,
    __hip_bfloat16* __restrict__ ctxb) {
    __shared__ __align__(16) __hip_bfloat16 Ks[64][72];
    __shared__ __align__(16) __hip_bfloat16 Vs[64][72];
    __shared__ __align__(16) __hip_bfloat16 Pw[4][16][72];
    __shared__ __align__(16) __hip_bfloat16 Gs[64][68];
    int id = blockIdx.x;
    int xcd = id & 7;
    int slot = id >> 3;             // 0..143
    int pair = xcd * 16 + slot / 9; // 0..127  (b*8+h, batches grouped)
    int sg = slot % 9;
    int b = pair >> 3;
    int h = pair & 7;
    int tid = threadIdx.x;
    int wave = tid >> 6, lane = tid & 63;
    int col = lane & 15, quad = lane >> 4;
    int q0b = sg * 64;
    int q0 = q0b + wave * 16;

    int qr = q0 + col; if (qr > T - 1) qr = T - 1;
    const __hip_bfloat16* qptr = qb + (size_t)(b * T + qr) * D + h * E + quad * 8;
    bf16x8 a0 = *(const bf16x8*)(const void*)qptr;
    bf16x8 a1 = *(const bf16x8*)(const void*)(qptr + 32);

    float S[4] = {0.f, 0.f, 0.f, 0.f};
    float G[4] = {0.f, 0.f, 0.f, 0.f};
    f32x4 o[4];
    #pragma unroll
    for (int j = 0; j < 4; ++j) o[j] = (f32x4){0.f, 0.f, 0.f, 0.f};

    const __hip_bfloat16* vbase = vt + (size_t)((b * H + h) * E) * VTS;

    for (int kc = 0; kc < NCHUNK; ++kc) {
        __syncthreads();
        #pragma unroll
        for (int i = 0; i < 2; ++i) {
            int idx = tid + i * 256;
            int r = idx >> 3, s = idx & 7;
            int kr = kc * 64 + r; int krc = kr > T - 1 ? T - 1 : kr;
            *(bf16x8*)(void*)&Ks[r][s * 8] =
                *(const bf16x8*)(const void*)(kb + (size_t)(b * T + krc) * D + h * E + s * 8);
            *(bf16x8*)(void*)&Vs[r][s * 8] =
                *(const bf16x8*)(const void*)(vbase + (size_t)r * VTS + kc * 64 + s * 8);
            bf16x8 gval;
            int grow = q0b + r;
            if (grow < N && kc < 8) {
                gval = *(const bf16x8*)(const void*)(gd + ((size_t)b * N + grow) * N + kc * 64 + s * 8);
            } else {
                gval = (bf16x8){0x3F00, 0x3F00, 0x3F00, 0x3F00, 0x3F00, 0x3F00, 0x3F00, 0x3F00};
            }
            *(bf16x8*)(void*)&Gs[r][s * 8] = gval;
        }
        __syncthreads();
        #pragma unroll
        for (int sub = 0; sub < 4; ++sub) {
            bf16x8 b0 = *(const bf16x8*)(const void*)&Ks[sub * 16 + col][quad * 8];
            bf16x8 b1 = *(const bf16x8*)(const void*)&Ks[sub * 16 + col][32 + quad * 8];
            f32x4 sc = (f32x4){0.f, 0.f, 0.f, 0.f};
            sc = __builtin_amdgcn_mfma_f32_16x16x32_bf16(a0, b0, sc, 0, 0, 0);
            sc = __builtin_amdgcn_mfma_f32_16x16x32_bf16(a1, b1, sc, 0, 0, 0);
            int key = kc * 64 + sub * 16 + col;
            #pragma unroll
            for (int r = 0; r < 4; ++r) {
                float v = sc[r] * 0.125f;
                if (key >= T) v = -1e30f;       // exp underflows to exactly 0
                float p = __expf(v);
                S[r] += p;
                float g = __bfloat162float(Gs[wave * 16 + quad * 4 + r][sub * 16 + col]);
                float t = p * g;
                G[r] += t;
                Pw[wave][quad * 4 + r][sub * 16 + col] = __float2bfloat16(t);
            }
        }
        #pragma unroll
        for (int ks = 0; ks < 2; ++ks) {
            bf16x8 pa = *(const bf16x8*)(const void*)&Pw[wave][col][ks * 32 + quad * 8];
            #pragma unroll
            for (int j = 0; j < 4; ++j) {
                bf16x8 bv = *(const bf16x8*)(const void*)&Vs[j * 16 + col][ks * 32 + quad * 8];
                o[j] = __builtin_amdgcn_mfma_f32_16x16x32_bf16(pa, bv, o[j], 0, 0, 0);
            }
        }
    }
    #pragma unroll
    for (int r = 0; r < 4; ++r) {
        #pragma unroll
        for (int d = 1; d < 16; d <<= 1) {
            S[r] += __shfl_xor(S[r], d, 64);
            G[r] += __shfl_xor(G[r], d, 64);
        }
    }
    float inv[4];
    #pragma unroll
    for (int r = 0; r < 4; ++r) inv[r] = 1.f / (G[r] + 1e-6f * S[r]);
    #pragma unroll
    for (int j = 0; j < 4; ++j)
        #pragma unroll
        for (int r = 0; r < 4; ++r) {
            int row = q0 + quad * 4 + r;
            if (row < T)
                ctxb[(size_t)(b * T + row) * D + h * E + j * 16 + col] =
                    __float2bfloat16(o[j][r] * inv[r]);
        }
}

// ---------- layernorm: bf16 in-place, wave-per-row, no barriers ----------
__global__ __launch_bounds__(256) void ln_kernel(__hip_bfloat16* __restrict__ xr,
                                                 const float* __restrict__ g,
                                                 const float* __restrict__ bb) {
    int row = blockIdx.x * 4 + (threadIdx.x >> 6);
    int lane = threadIdx.x & 63;
    __hip_bfloat16* base = xr + (size_t)row * D + lane * 8;
    __align__(16) __hip_bfloat16 u[8];
    *(bf16x8*)(void*)u = *(const bf16x8*)(const void*)base;
    float v[8];
    float s = 0.f, ss = 0.f;
    #pragma unroll
    for (int i = 0; i < 8; ++i) {
        v[i] = __bfloat162float(u[i]);
        s += v[i];
        ss += v[i] * v[i];
    }
    #pragma unroll
    for (int d = 1; d < 64; d <<= 1) {
        s += __shfl_xor(s, d, 64);
        ss += __shfl_xor(ss, d, 64);
    }
    float m = s * (1.f / (float)D);
    float var = ss * (1.f / (float)D) - m * m;
    float rstd = rsqrtf(fmaxf(var, 0.f) + 1e-5f);
    float4 g0 = *(const float4*)(g + lane * 8);
    float4 g1 = *(const float4*)(g + lane * 8 + 4);
    float4 b0 = *(const float4*)(bb + lane * 8);
    float4 b1 = *(const float4*)(bb + lane * 8 + 4);
    float gg[8] = {g0.x, g0.y, g0.z, g0.w, g1.x, g1.y, g1.z, g1.w};
    float bz[8] = {b0.x, b0.y, b0.z, b0.w, b1.x, b1.y, b1.z, b1.w};
    __align__(16) __hip_bfloat16 ot[8];
    #pragma unroll
    for (int i = 0; i < 8; ++i)
        ot[i] = __float2bfloat16((v[i] - m) * rstd * gg[i] + bz[i]);
    *(bf16x8*)(void*)base = *(const bf16x8*)(const void*)ot;
}

// ---------- proj GEMM with fused transpose + RevIN inverse epilogue ----------
__global__ __launch_bounds__(256, 2) void proj_revin_gemm(
    const __hip_bfloat16* __restrict__ A, const __hip_bfloat16* __restrict__ Wt,
    const float* __restrict__ pb, const float* __restrict__ beta,
    const float* __restrict__ gamma, const float* __restrict__ mean,
    const float* __restrict__ stdv, float* __restrict__ out, int nbm, int nbn) {
    const int M = B * T, K = D, Nn = PRED;
    __shared__ __align__(16) __hip_bfloat16 As[64 * 32];
    __shared__ __align__(16) __hip_bfloat16 Bs[64 * 32];
    int id = blockIdx.x;
    int xcd = id & 7, slot = id >> 3;
    int bmb = xcd + 8 * (slot / nbn);
    int bnb = slot % nbn;
    if (bmb >= nbm) return;
    int bm = bmb * 64;
    int bn = bnb * 64;
    int tid = threadIdx.x;
    int lane = tid & 63;
    int wave = tid >> 6;
    int col = lane & 15;
    int quad = lane >> 4;
    int wm = (wave & 1) * 32;
    int wn = (wave >> 1) * 32;
    f32x4 acc[2][2];
    #pragma unroll
    for (int i = 0; i < 2; ++i)
        #pragma unroll
        for (int j = 0; j < 2; ++j) acc[i][j] = (f32x4){0.f, 0.f, 0.f, 0.f};

    for (int k0 = 0; k0 < K; k0 += 32) {
        {
            int cbase = wave * 64;
            int c = cbase + lane;
            int row = c >> 2;
            int g = (c & 3) ^ SWZM(row);
            int gm = bm + row; if (gm >= M) gm = M - 1;
            const __hip_bfloat16* ga = A + (size_t)gm * K + k0 + g * 8;
            __builtin_amdgcn_global_load_lds(
                (const __attribute__((address_space(1))) void*)ga,
                (__attribute__((address_space(3))) void*)(As + (size_t)cbase * 8), 16, 0, 0);
            int gn = bn + row; if (gn >= Nn) gn = Nn - 1;
            const __hip_bfloat16* gb = Wt + (size_t)gn * K + k0 + g * 8;
            __builtin_amdgcn_global_load_lds(
                (const __attribute__((address_space(1))) void*)gb,
                (__attribute__((address_space(3))) void*)(Bs + (size_t)cbase * 8), 16, 0, 0);
        }
        __syncthreads();
        bf16x8 af[2], bfr[2];
        #pragma unroll
        for (int i = 0; i < 2; ++i) {
            int ra = wm + i * 16 + col;
            af[i] = *(const bf16x8*)(const void*)&As[(ra * 4 + (quad ^ SWZM(ra))) * 8];
        }
        #pragma unroll
        for (int j = 0; j < 2; ++j) {
            int rb = wn + j * 16 + col;
            bfr[j] = *(const bf16x8*)(const void*)&Bs[(rb * 4 + (quad ^ SWZM(rb))) * 8];
        }
        #pragma unroll
        for (int i = 0; i < 2; ++i)
            #pragma unroll
            for (int j = 0; j < 2; ++j)
                acc[i][j] = __builtin_amdgcn_mfma_f32_16x16x32_bf16(af[i], bfr[j], acc[i][j], 0, 0, 0);
        __syncthreads();
    }
    #pragma unroll
    for (int i = 0; i < 2; ++i) {
        int gmb = bm + wm + i * 16 + quad * 4;
        int b = gmb / T;
        int n0 = gmb - b * T;
        #pragma unroll
        for (int j = 0; j < 2; ++j) {
            int gn = bn + wn + j * 16 + col;   // prediction index p
            if (gn >= PRED) continue;
            float bs = pb[gn];
            #pragma unroll
            for (int r = 0; r < 4; ++r) {
                int gm = gmb + r;
                if (gm >= M) continue;
                int n = n0 + r;
                if (n >= N) continue;          // mark-token rows dropped
                int bn_ = b * N + n;
                float v = acc[i][j][r] + bs;
                out[((size_t)b * PRED + gn) * N + n] =
                    (v - beta[n]) * (stdv[bn_] / (gamma[n] + 1e-5f)) + mean[bn_];
            }
        }
    }
}

static inline int swz_grid(int nbm, int nbn) { return 8 * ((nbm + 7) / 8) * nbn; }

extern "C" void kernel_launch(void* const* d_in, const int* in_sizes, int n_in,
                              void* d_out, int out_size, void* d_ws, size_t ws_size,
                              hipStream_t stream) {
    const float* x_enc  = (const float*)d_in[0];
    const float* x_mark = (const float*)d_in[1];
    const float* gamma  = (const float*)d_in[4];
    const float* beta   = (const float*)d_in[5];
    const float* tp_w1  = (const float*)d_in[6];
    const float* tp_b1  = (const float*)d_in[7];
    const float* tp_w2  = (const float*)d_in[8];
    const float* tp_b2  = (const float*)d_in[9];
    const float* emb_w  = (const float*)d_in[10];
    const float* emb_b  = (const float*)d_in[11];
    const float* wq = (const float*)d_in[12];
    const float* bq = (const float*)d_in[13];
    const float* wk = (const float*)d_in[14];
    const float* bk = (const float*)d_in[15];
    const float* wv = (const float*)d_in[16];
    const float* bv = (const float*)d_in[17];
    const float* wo = (const float*)d_in[18];
    const float* bo = (const float*)d_in[19];
    const float* w1 = (const float*)d_in[20];
    const float* b1 = (const float*)d_in[21];
    const float* w2 = (const float*)d_in[22];
    const float* b2 = (const float*)d_in[23];
    const float* ln1g = (const float*)d_in[24];
    const float* ln1b = (const float*)d_in[25];
    const float* ln2g = (const float*)d_in[26];
    const float* ln2b = (const float*)d_in[27];
    const float* normg = (const float*)d_in[28];
    const float* normb = (const float*)d_in[29];
    const float* proj_w = (const float*)d_in[30];
    const float* proj_b = (const float*)d_in[31];

    char* ws = (char*)d_ws;
    float* mean = (float*)(ws + WS_MEAN);
    float* stdv = (float*)(ws + WS_STD);
    __hip_bfloat16* gd  = (__hip_bfloat16*)(ws + WS_GD);
    __hip_bfloat16* R   = (__hip_bfloat16*)(ws + WS_X);   // bf16 residual stream
    __hip_bfloat16* ctxb = (__hip_bfloat16*)(ws + WS_XB);
    __hip_bfloat16* wts = (__hip_bfloat16*)(ws + WS_WTS);
    __hip_bfloat16* qbuf = (__hip_bfloat16*)(ws + WS_QB);
    __hip_bfloat16* kbuf = (__hip_bfloat16*)(ws + WS_KB);
    __hip_bfloat16* vt   = (__hip_bfloat16*)(ws + WS_VT);
    float* xt  = (float*)(ws + WS_KB);
    __hip_bfloat16* ntb = (__hip_bfloat16*)(ws + WS_VT);
    __hip_bfloat16* tokb = (__hip_bfloat16*)(ws + WS_QB);
    __hip_bfloat16* ffnb = (__hip_bfloat16*)(ws + WS_QB);

    revin_stats_kernel<<<(B * N + 255) / 256, 256, 0, stream>>>(x_enc, mean, stdv);
    norm_transpose_kernel<<<(B * N * L + 255) / 256, 256, 0, stream>>>(x_enc, mean, stdv, gamma, beta,
                                                                       xt, tokb);
    build_mark_kernel<<<(B * NMARK * L + 255) / 256, 256, 0, stream>>>(x_mark, tokb);
    trend_nt_kernel<<<B * N, 128, 0, stream>>>(xt, tp_w1, tp_b1, tp_w2, tp_b2, ntb);
    guide_mfma_kernel<<<B * 64, 256, 0, stream>>>(ntb, gd);
    // vt aliases ntb: stale bytes as bf16 can be NaN in pad tokens; 0*NaN=NaN
    // in the PV MFMA. Zero once per launch (layer GEMMs rewrite tokens 0..515).
    hipMemsetAsync(vt, 0, VT_BYTES, stream);
    wconv_kernel<<<6240, 256, 0, stream>>>(wq, wk, wv, wo, w1, w2, emb_w, proj_w, wts);

    const int M = B * T;                   // 8256
    const int NBM64 = (M + 63) / 64;       // 129
    const int NBM128 = (M + 127) / 128;    // 65
    mfma_gemm_t<64, 64><<<swz_grid(NBM64, 8), 256, 0, stream>>>(
        tokb, wts + WT_EMB, emb_b, nullptr, R, M, D, L, 0, NBM64, 8);
    for (int i = 0; i < 2; ++i) {
        const __hip_bfloat16* qkvT = wts + WT_QKV + (size_t)i * 1536 * 512;
        const __hip_bfloat16* woT  = wts + WT_WO + (size_t)i * D * D;
        qkv_gemm<<<swz_grid(NBM64, 24), 256, 0, stream>>>(
            R, qkvT, bq + i * D, bk + i * D, bv + i * D, qbuf, kbuf, vt, NBM64, 24);
        attn_flash_kernel<<<B * H * 9, 256, 0, stream>>>(qbuf, kbuf, vt, gd, ctxb);
        mfma_gemm_t<64, 64><<<swz_grid(NBM64, 8), 256, 0, stream>>>(
            ctxb, woT, bo + i * D, R, R, M, D, D, 0, NBM64, 8);
        ln_kernel<<<M / 4, 256, 0, stream>>>(R, ln1g + i * D, ln1b + i * D);
        mfma_gemm_t<128, 128><<<swz_grid(NBM128, 16), 256, 0, stream>>>(
            R, wts + WT_W1 + (size_t)i * DFF * D, b1 + i * DFF, nullptr,
            ffnb, M, DFF, D, 1, NBM128, 16);
        mfma_gemm_t<64, 64><<<swz_grid(NBM64, 8), 256, 0, stream>>>(
            ffnb, wts + WT_W2 + (size_t)i * DFF * D, b2 + i * D, R, R,
            M, D, DFF, 0, NBM64, 8);
        ln_kernel<<<M / 4, 256, 0, stream>>>(R, ln2g + i * D, ln2b + i * D);
    }
    ln_kernel<<<M / 4, 256, 0, stream>>>(R, normg, normb);
    proj_revin_gemm<<<swz_grid(NBM64, 2), 256, 0, stream>>>(
        R, wts + WT_PROJ, proj_b, beta, gamma, mean, stdv, (float*)d_out, NBM64, 2);
}